// Round 1
// baseline (472.750 us; speedup 1.0000x reference)
//
#include <hip/hip_runtime.h>
#include <hip/hip_bf16.h>

#define DEV __device__ __forceinline__

typedef __bf16 bf16x8 __attribute__((ext_vector_type(8)));
typedef float f32x4 __attribute__((ext_vector_type(4)));

static constexpr int kB = 2, kT = 2048, kD = 2048, kH = 16, kHD = 128;
static constexpr int kBT = kB * kT;  // 4096

DEV unsigned short f2bf(float f) {
  union { __hip_bfloat16 h; unsigned short u; } cv;
  cv.h = __float2bfloat16(f);
  return cv.u;
}

// async global->LDS, 16B per lane. LDS dest must be wave-uniform base + lane*16.
DEV void gl_lds16(const void* g, void* l) {
  __builtin_amdgcn_global_load_lds(
      (const __attribute__((address_space(1))) unsigned int*)g,
      (__attribute__((address_space(3))) unsigned int*)l, 16, 0, 0);
}

#define MFMA(a, b, c) __builtin_amdgcn_mfma_f32_16x16x32_bf16(a, b, c, 0, 0, 0)

// ---------------- fp32 -> bf16 conversion (vectorized x4) ----------------
__global__ __launch_bounds__(256) void cvt_kernel(const float* __restrict__ src,
                                                  unsigned short* __restrict__ dst,
                                                  int n4) {
  int i = blockIdx.x * 256 + threadIdx.x;
  if (i >= n4) return;
  float4 v = ((const float4*)src)[i];
  ushort4 o;
  o.x = f2bf(v.x); o.y = f2bf(v.y); o.z = f2bf(v.z); o.w = f2bf(v.w);
  ((ushort4*)dst)[i] = o;
}

// ------------- V^T = (x * c) transposed to [b][h][hd][T], bf16 -------------
// top_k with TOPK==NVK==4 selects ALL rows -> c[d] = 2*sum_{k<4} v_embed[k][d]
__global__ __launch_bounds__(256) void make_vt_kernel(
    const float* __restrict__ x, const float* __restrict__ v_embed,
    unsigned short* __restrict__ vt) {
  const int t = blockIdx.x * 64 + (threadIdx.x & 63);
  const int h = blockIdx.y, b = blockIdx.z;
  for (int hd = (threadIdx.x >> 6); hd < kHD; hd += 4) {
    const int d = h * kHD + hd;
    const float c = 2.f * (v_embed[d] + v_embed[kD + d] + v_embed[2 * kD + d] +
                           v_embed[3 * kD + d]);
    const float v = x[(size_t)(b * kT + t) * kD + d] * c;
    vt[((size_t)((b * kH + h) * kHD + hd)) * kT + t] = f2bf(v);  // t-coalesced
  }
}

// ---------------- C[m,n] = sum_k A[m,k]*B[n,k] + bias[n] ----------------
// 128x128 tile, BK=32, 4 waves (2x2), 16x16x32 bf16 MFMA, global_load_lds w=16,
// XOR chunk swizzle (pos = row*4 + (c ^ (row&3))) for bank-conflict reduction.
template <bool BF16OUT>
__global__ __launch_bounds__(256, 3) void gemm_bt(
    const unsigned short* __restrict__ A, const unsigned short* __restrict__ Bm,
    const float* __restrict__ bias, void* __restrict__ Cout) {
  constexpr int N = kD, K = kD;
  __shared__ unsigned short As[128 * 32], Bs[128 * 32];
  const int tid = threadIdx.x;
  const int lane = tid & 63, wave = tid >> 6;
  const int wr = wave >> 1, wc = wave & 1;
  const int m0 = blockIdx.y * 128, n0 = blockIdx.x * 128;
  const int frow = lane & 15, fc = lane >> 4;

  f32x4 acc[4][4];
  for (int i = 0; i < 4; i++)
    for (int j = 0; j < 4; j++)
      for (int r = 0; r < 4; r++) acc[i][j][r] = 0.f;

  const int r0 = tid >> 2, c0 = (tid & 3) ^ (r0 & 3);
  const int p1 = tid + 256;
  const int r1 = p1 >> 2, c1 = (p1 & 3) ^ (r1 & 3);

  const unsigned short* Ab = A + (size_t)m0 * K;
  const unsigned short* Bb = Bm + (size_t)n0 * K;

  for (int k0 = 0; k0 < K; k0 += 32) {
    __syncthreads();
    gl_lds16(Ab + (size_t)r0 * K + k0 + c0 * 8, As + tid * 8);
    gl_lds16(Ab + (size_t)r1 * K + k0 + c1 * 8, As + p1 * 8);
    gl_lds16(Bb + (size_t)r0 * K + k0 + c0 * 8, Bs + tid * 8);
    gl_lds16(Bb + (size_t)r1 * K + k0 + c1 * 8, Bs + p1 * 8);
    __syncthreads();
    bf16x8 af[4], bfr[4];
    for (int mi = 0; mi < 4; mi++) {
      int row = wr * 64 + mi * 16 + frow;
      af[mi] = *(const bf16x8*)(As + (row * 4 + (fc ^ (row & 3))) * 8);
    }
    for (int ni = 0; ni < 4; ni++) {
      int row = wc * 64 + ni * 16 + frow;
      bfr[ni] = *(const bf16x8*)(Bs + (row * 4 + (fc ^ (row & 3))) * 8);
    }
    for (int mi = 0; mi < 4; mi++)
      for (int ni = 0; ni < 4; ni++)
        acc[mi][ni] = MFMA(af[mi], bfr[ni], acc[mi][ni]);
  }
  // epilogue: C/D layout col=lane&15, row=(lane>>4)*4+reg
  for (int ni = 0; ni < 4; ni++) {
    const int n = n0 + wc * 64 + ni * 16 + frow;
    const float bs = bias[n];
    for (int mi = 0; mi < 4; mi++) {
      const int mb = m0 + wr * 64 + mi * 16 + fc * 4;
      for (int r = 0; r < 4; r++) {
        const float v = acc[mi][ni][r] + bs;
        if (BF16OUT)
          ((unsigned short*)Cout)[(size_t)(mb + r) * N + n] = f2bf(v);
        else
          ((float*)Cout)[(size_t)(mb + r) * N + n] = v;
      }
    }
  }
}

// ---------------- flash attention, causal ----------------
// grid (16 qb, 16 h, 2 b); 128-row Q tile (32 rows/wave), 64-key K tiles.
__global__ __launch_bounds__(256, 2) void attn_kernel(
    const unsigned short* __restrict__ Q, const unsigned short* __restrict__ Kb,
    const unsigned short* __restrict__ Vt, unsigned short* __restrict__ O) {
  __shared__ unsigned short sK[64 * 128];   // [key][hd], chunk-swizzled
  __shared__ unsigned short sV[128 * 64];   // V^T [hd][key], chunk-swizzled
  __shared__ unsigned short sP[128 * 72];   // P, padded stride 72
  const int tid = threadIdx.x, lane = tid & 63, w = tid >> 6;
  const int qb = 15 - blockIdx.x;  // heavy blocks dispatch first
  const int h = blockIdx.y, b = blockIdx.z;
  const int q0 = qb * 128;
  const int frow = lane & 15, fc = lane >> 4;

  // Q fragments (A-operand): rows w*32+mi*16+frow, k = kk*32 + fc*8 + j
  bf16x8 qf[2][4];
  const unsigned short* Qbase =
      Q + (size_t)(b * kT + q0 + w * 32) * kD + h * kHD;
  for (int mi = 0; mi < 2; mi++)
    for (int kk = 0; kk < 4; kk++)
      qf[mi][kk] =
          *(const bf16x8*)(Qbase + (size_t)(mi * 16 + frow) * kD + kk * 32 + fc * 8);

  f32x4 oacc[2][8];
  for (int mi = 0; mi < 2; mi++)
    for (int ni = 0; ni < 8; ni++)
      for (int r = 0; r < 4; r++) oacc[mi][ni][r] = 0.f;
  float m_i[2][4], l_i[2][4];
  for (int mi = 0; mi < 2; mi++)
    for (int r = 0; r < 4; r++) { m_i[mi][r] = -1e30f; l_i[mi][r] = 0.f; }

  const float scale = 0.08838834764831845f;  // 1/sqrt(128)
  const int nkb = qb * 2 + 2;

  for (int kb = 0; kb < nkb; kb++) {
    const int k0 = kb * 64;
    __syncthreads();
    for (int i = 0; i < 4; i++) {
      const int p = tid + i * 256;
      const int key = p >> 4, hc = (p & 15) ^ (key & 15);
      gl_lds16(Kb + (size_t)(b * kT + k0 + key) * kD + h * kHD + hc * 8, sK + p * 8);
      const int hd = p >> 3, kc = (p & 7) ^ (hd & 7);
      gl_lds16(Vt + ((size_t)((b * kH + h) * kHD + hd)) * kT + k0 + kc * 8, sV + p * 8);
    }
    __syncthreads();

    // S = Q K^T  (rows w*32.., cols k0..k0+63)
    f32x4 s[2][4];
    for (int mi = 0; mi < 2; mi++)
      for (int ni = 0; ni < 4; ni++)
        for (int r = 0; r < 4; r++) s[mi][ni][r] = 0.f;
    for (int ni = 0; ni < 4; ni++) {
      const int key = ni * 16 + frow;
      for (int kk = 0; kk < 4; kk++) {
        bf16x8 kf =
            *(const bf16x8*)(sK + (key * 16 + ((kk * 4 + fc) ^ (key & 15))) * 8);
        s[0][ni] = MFMA(qf[0][kk], kf, s[0][ni]);
        s[1][ni] = MFMA(qf[1][kk], kf, s[1][ni]);
      }
    }
    // scale + causal mask + online softmax (row stats within 16-lane groups)
    for (int mi = 0; mi < 2; mi++) {
      for (int r = 0; r < 4; r++) {
        const int row = q0 + w * 32 + mi * 16 + fc * 4 + r;
        float mx = -1e30f;
        for (int ni = 0; ni < 4; ni++) {
          const int col = k0 + ni * 16 + frow;
          float v = s[mi][ni][r] * scale;
          v = (col <= row) ? v : -1e30f;
          s[mi][ni][r] = v;
          mx = fmaxf(mx, v);
        }
        for (int off = 1; off < 16; off <<= 1)
          mx = fmaxf(mx, __shfl_xor(mx, off, 64));
        const float mn = fmaxf(m_i[mi][r], mx);
        const float alpha = __expf(m_i[mi][r] - mn);
        float rs = 0.f;
        for (int ni = 0; ni < 4; ni++) {
          const float p = __expf(s[mi][ni][r] - mn);
          s[mi][ni][r] = p;
          rs += p;
        }
        for (int off = 1; off < 16; off <<= 1)
          rs += __shfl_xor(rs, off, 64);
        m_i[mi][r] = mn;
        l_i[mi][r] = l_i[mi][r] * alpha + rs;
        for (int ni = 0; ni < 8; ni++) oacc[mi][ni][r] *= alpha;
      }
    }
    // P: C-layout regs -> LDS (A-operand layout for PV)
    for (int mi = 0; mi < 2; mi++)
      for (int ni = 0; ni < 4; ni++)
        for (int r = 0; r < 4; r++)
          sP[(w * 32 + mi * 16 + fc * 4 + r) * 72 + ni * 16 + frow] =
              f2bf(s[mi][ni][r]);
    __syncthreads();  // order cross-lane P write->read (compiler may reorder DS)
    // O += P V   (B-operand = V^T, key-contiguous)
    for (int kk = 0; kk < 2; kk++) {
      bf16x8 pf0 = *(const bf16x8*)(sP + (w * 32 + frow) * 72 + kk * 32 + fc * 8);
      bf16x8 pf1 =
          *(const bf16x8*)(sP + (w * 32 + 16 + frow) * 72 + kk * 32 + fc * 8);
      for (int ni = 0; ni < 8; ni++) {
        const int hd = ni * 16 + frow;
        bf16x8 vf =
            *(const bf16x8*)(sV + (hd * 8 + ((kk * 4 + fc) ^ (hd & 7))) * 8);
        oacc[0][ni] = MFMA(pf0, vf, oacc[0][ni]);
        oacc[1][ni] = MFMA(pf1, vf, oacc[1][ni]);
      }
    }
  }
  // epilogue: O / l -> [b, t, h*128+hd] bf16
  for (int mi = 0; mi < 2; mi++)
    for (int r = 0; r < 4; r++) {
      const int row = q0 + w * 32 + mi * 16 + fc * 4 + r;
      const float inv = 1.f / l_i[mi][r];
      for (int ni = 0; ni < 8; ni++)
        O[(size_t)(b * kT + row) * kD + h * kHD + ni * 16 + frow] =
            f2bf(oacc[mi][ni][r] * inv);
    }
}

extern "C" void kernel_launch(void* const* d_in, const int* in_sizes, int n_in,
                              void* d_out, int out_size, void* d_ws, size_t ws_size,
                              hipStream_t stream) {
  const float* x       = (const float*)d_in[0];
  const float* Wq      = (const float*)d_in[1];
  const float* bq      = (const float*)d_in[2];
  const float* Wk      = (const float*)d_in[3];
  const float* bk      = (const float*)d_in[4];
  // d_in[5] Wvq, d_in[6] bvq, d_in[7] v_keys: dead (top_k selects all NVK)
  const float* v_embed = (const float*)d_in[8];
  const float* Wo      = (const float*)d_in[9];
  const float* bo      = (const float*)d_in[10];
  float* out = (float*)d_out;

  char* w = (char*)d_ws;
  unsigned short* xb  = (unsigned short*)w; w += (size_t)kBT * kD * 2;  // 16MB
  unsigned short* qb  = (unsigned short*)w; w += (size_t)kBT * kD * 2;
  unsigned short* kb  = (unsigned short*)w; w += (size_t)kBT * kD * 2;
  unsigned short* ob  = (unsigned short*)w; w += (size_t)kBT * kD * 2;
  unsigned short* vtb = (unsigned short*)w; w += (size_t)kBT * kD * 2;
  unsigned short* wqb = (unsigned short*)w; w += (size_t)kD * kD * 2;   // 8MB
  unsigned short* wkb = (unsigned short*)w; w += (size_t)kD * kD * 2;
  unsigned short* wob = (unsigned short*)w; w += (size_t)kD * kD * 2;

  cvt_kernel<<<kBT * kD / 1024, 256, 0, stream>>>(x, xb, kBT * kD / 4);
  cvt_kernel<<<kD * kD / 1024, 256, 0, stream>>>(Wq, wqb, kD * kD / 4);
  cvt_kernel<<<kD * kD / 1024, 256, 0, stream>>>(Wk, wkb, kD * kD / 4);
  cvt_kernel<<<kD * kD / 1024, 256, 0, stream>>>(Wo, wob, kD * kD / 4);
  make_vt_kernel<<<dim3(kT / 64, kH, kB), 256, 0, stream>>>(x, v_embed, vtb);

  dim3 ggrid(kD / 128, kBT / 128);  // (N/128, M/128) = (16, 32)
  gemm_bt<true><<<ggrid, 256, 0, stream>>>(xb, wqb, bq, qb);
  gemm_bt<true><<<ggrid, 256, 0, stream>>>(xb, wkb, bk, kb);

  attn_kernel<<<dim3(16, kH, kB), 256, 0, stream>>>(qb, kb, vtb, ob);

  gemm_bt<false><<<ggrid, 256, 0, stream>>>(ob, wob, bo, out);
}

// Round 4
// 368.472 us; speedup vs baseline: 1.2830x; 1.2830x over previous
//
#include <hip/hip_runtime.h>
#include <hip/hip_bf16.h>

#define DEV __device__ __forceinline__

typedef __bf16 bf16x8 __attribute__((ext_vector_type(8)));
typedef __bf16 bf16x4 __attribute__((ext_vector_type(4)));
typedef float f32x4 __attribute__((ext_vector_type(4)));

static constexpr int kB = 2, kT = 2048, kD = 2048, kH = 16, kHD = 128;
static constexpr int kBT = kB * kT;  // 4096

// fast 2^x: v_exp_f32 computes exp2 natively on gfx950
#if __has_builtin(__builtin_amdgcn_exp2f)
DEV float fast_exp2(float x) { return __builtin_amdgcn_exp2f(x); }
#else
DEV float fast_exp2(float x) { return exp2f(x); }
#endif

DEV unsigned short f2bf(float f) {
  union { __hip_bfloat16 h; unsigned short u; } cv;
  cv.h = __float2bfloat16(f);
  return cv.u;
}

// async global->LDS, 16B per lane. LDS dest must be wave-uniform base + lane*16.
DEV void gl_lds16(const void* g, void* l) {
  __builtin_amdgcn_global_load_lds(
      (const __attribute__((address_space(1))) unsigned int*)g,
      (__attribute__((address_space(3))) unsigned int*)l, 16, 0, 0);
}

#define MFMA(a, b, c) __builtin_amdgcn_mfma_f32_16x16x32_bf16(a, b, c, 0, 0, 0)

// ---------------- fp32 -> bf16 conversion (vectorized x4) ----------------
__global__ __launch_bounds__(256) void cvt_kernel(const float* __restrict__ src,
                                                  unsigned short* __restrict__ dst,
                                                  int n4) {
  int i = blockIdx.x * 256 + threadIdx.x;
  if (i >= n4) return;
  float4 v = ((const float4*)src)[i];
  ushort4 o;
  o.x = f2bf(v.x); o.y = f2bf(v.y); o.z = f2bf(v.z); o.w = f2bf(v.w);
  ((ushort4*)dst)[i] = o;
}

// three equal-size fp32->bf16 conversions in one dispatch (y picks buffer)
__global__ __launch_bounds__(256) void cvt3_kernel(
    const float* __restrict__ s0, const float* __restrict__ s1,
    const float* __restrict__ s2, unsigned short* __restrict__ d0,
    unsigned short* __restrict__ d1, unsigned short* __restrict__ d2, int n4) {
  const float* s = blockIdx.y == 0 ? s0 : blockIdx.y == 1 ? s1 : s2;
  unsigned short* d = blockIdx.y == 0 ? d0 : blockIdx.y == 1 ? d1 : d2;
  int i = blockIdx.x * 256 + threadIdx.x;
  if (i >= n4) return;
  float4 v = ((const float4*)s)[i];
  ushort4 o;
  o.x = f2bf(v.x); o.y = f2bf(v.y); o.z = f2bf(v.z); o.w = f2bf(v.w);
  ((ushort4*)d)[i] = o;
}

// ------------- V^T = (x * c) transposed to [b][h][hd][T], bf16 -------------
// top_k with TOPK==NVK==4 selects ALL rows -> c[d] = 2*sum_{k<4} v_embed[k][d]
__global__ __launch_bounds__(256) void make_vt_kernel(
    const float* __restrict__ x, const float* __restrict__ v_embed,
    unsigned short* __restrict__ vt) {
  const int t = blockIdx.x * 64 + (threadIdx.x & 63);
  const int h = blockIdx.y, b = blockIdx.z;
  for (int hd = (threadIdx.x >> 6); hd < kHD; hd += 4) {
    const int d = h * kHD + hd;
    const float c = 2.f * (v_embed[d] + v_embed[kD + d] + v_embed[2 * kD + d] +
                           v_embed[3 * kD + d]);
    const float v = x[(size_t)(b * kT + t) * kD + d] * c;
    vt[((size_t)((b * kH + h) * kHD + hd)) * kT + t] = f2bf(v);  // t-coalesced
  }
}

// ---------------- C[m,n] = (sum_k A[m,k]*B[n,k] + bias[n]) * scale ----------
// 128x128 tile, BK=32, 4 waves (2x2), 16x16x32 bf16 MFMA, global_load_lds w=16,
// XOR chunk swizzle for bank-conflict reduction.
template <bool BF16OUT, bool FUSED2>
__global__ __launch_bounds__(256, 3) void gemm_bt(
    const unsigned short* __restrict__ A, const unsigned short* __restrict__ B1,
    const unsigned short* __restrict__ B2, const float* __restrict__ bias1,
    const float* __restrict__ bias2, void* __restrict__ C1, void* __restrict__ C2,
    float scale1, float scale2) {
  constexpr int N = kD, K = kD;
  __shared__ __align__(16) unsigned short As[128 * 32], Bs[128 * 32];
  const unsigned short* Bm = (FUSED2 && blockIdx.z) ? B2 : B1;
  const float* bias = (FUSED2 && blockIdx.z) ? bias2 : bias1;
  void* Cout = (FUSED2 && blockIdx.z) ? C2 : C1;
  const float scale = (FUSED2 && blockIdx.z) ? scale2 : scale1;
  const int tid = threadIdx.x;
  const int lane = tid & 63, wave = tid >> 6;
  const int wr = wave >> 1, wc = wave & 1;
  const int m0 = blockIdx.y * 128, n0 = blockIdx.x * 128;
  const int frow = lane & 15, fc = lane >> 4;

  f32x4 acc[4][4];
  for (int i = 0; i < 4; i++)
    for (int j = 0; j < 4; j++)
      for (int r = 0; r < 4; r++) acc[i][j][r] = 0.f;

  const int r0 = tid >> 2, c0 = (tid & 3) ^ (r0 & 3);
  const int p1 = tid + 256;
  const int r1 = p1 >> 2, c1 = (p1 & 3) ^ (r1 & 3);

  const unsigned short* Ab = A + (size_t)m0 * K;
  const unsigned short* Bb = Bm + (size_t)n0 * K;

  for (int k0 = 0; k0 < K; k0 += 32) {
    __syncthreads();
    gl_lds16(Ab + (size_t)r0 * K + k0 + c0 * 8, As + tid * 8);
    gl_lds16(Ab + (size_t)r1 * K + k0 + c1 * 8, As + p1 * 8);
    gl_lds16(Bb + (size_t)r0 * K + k0 + c0 * 8, Bs + tid * 8);
    gl_lds16(Bb + (size_t)r1 * K + k0 + c1 * 8, Bs + p1 * 8);
    __syncthreads();
    bf16x8 af[4], bfr[4];
    for (int mi = 0; mi < 4; mi++) {
      int row = wr * 64 + mi * 16 + frow;
      af[mi] = *(const bf16x8*)(As + (row * 4 + (fc ^ (row & 3))) * 8);
    }
    for (int ni = 0; ni < 4; ni++) {
      int row = wc * 64 + ni * 16 + frow;
      bfr[ni] = *(const bf16x8*)(Bs + (row * 4 + (fc ^ (row & 3))) * 8);
    }
    for (int mi = 0; mi < 4; mi++)
      for (int ni = 0; ni < 4; ni++)
        acc[mi][ni] = MFMA(af[mi], bfr[ni], acc[mi][ni]);
  }
  // epilogue: C/D layout col=lane&15, row=(lane>>4)*4+reg
  for (int ni = 0; ni < 4; ni++) {
    const int n = n0 + wc * 64 + ni * 16 + frow;
    const float bs = bias[n];
    for (int mi = 0; mi < 4; mi++) {
      const int mb = m0 + wr * 64 + mi * 16 + fc * 4;
      for (int r = 0; r < 4; r++) {
        const float v = (acc[mi][ni][r] + bs) * scale;
        if (BF16OUT)
          ((unsigned short*)Cout)[(size_t)(mb + r) * N + n] = f2bf(v);
        else
          ((float*)Cout)[(size_t)(mb + r) * N + n] = v;
      }
    }
  }
}

// ---------------- flash attention v2, causal, S^T formulation ----------------
// Q is PRE-SCALED by (1/sqrt(HD))*log2(e); softmax in exp2 domain.
// Each block: two paired 64-row q-tiles (qt=31-i then qt=i) -> uniform 33 k-tile
// units/block. 4 waves; wave owns 16 q columns. Double-buffered K/V LDS, one
// barrier per k-tile, prefetch overlaps compute.
// S^T via MFMA(A=K-frag, B=Q-frag): lane holds S^T[key=(l>>4)*4+r][q=l&15];
// softmax over keys = in-register + 2 shfl_xor. PV uses ONLY the verified
// 16x16x32 MFMA via slot remap: chunk c slot (g,j) <-> key 32c+(j>>2)*16+4g+(j&3)
// so B-frag = {pk[2c],pk[2c+1]} (C-regs as-is) and A-frag = two b64 sV reads.
__global__ __launch_bounds__(256, 2) void attn2_kernel(
    const unsigned short* __restrict__ Q, const unsigned short* __restrict__ Kg,
    const unsigned short* __restrict__ Vt, unsigned short* __restrict__ O) {
  __shared__ __align__(16) unsigned short sK[2][64 * 128];  // [key][hd], swizzled
  __shared__ __align__(16) unsigned short sV[2][64 * 128];  // [hd][key], swizzled
  const int tid = threadIdx.x, l = tid & 63, w = tid >> 6;
  const int g = l >> 4, q15 = l & 15;
  const int pi = blockIdx.x, h = blockIdx.y, b = blockIdx.z;

  for (int half = 0; half < 2; half++) {
    const int qt = half == 0 ? (31 - pi) : pi;
    const int q0 = qt * 64;
    const int nkb = qt + 1;
    const int q = q0 + w * 16 + q15;  // this lane's q column

    __syncthreads();  // buffer reuse safety across halves
    // stage tile 0 -> buf 0
    for (int i = 0; i < 4; i++) {
      const int idx = tid + i * 256;
      const int key = idx >> 4, cc = (idx & 15) ^ (key & 15);
      gl_lds16(Kg + (size_t)(b * kT + key) * kD + h * kHD + cc * 8,
               &sK[0][idx * 8]);
    }
    for (int i = 0; i < 4; i++) {
      const int idx = tid + i * 256;
      const int hd = idx >> 3, cc = (idx & 7) ^ (hd & 7);
      gl_lds16(Vt + ((size_t)((b * kH + h) * kHD + hd)) * kT + cc * 8,
               &sV[0][idx * 8]);
    }

    // Q B-frags (lane holds Q[q][hd = kk*32 + g*8 .. +7])
    bf16x8 qf[4];
    const unsigned short* Qrow = Q + (size_t)(b * kT + q) * kD + h * kHD;
#pragma unroll
    for (int kk = 0; kk < 4; kk++)
      qf[kk] = *(const bf16x8*)(Qrow + kk * 32 + g * 8);

    f32x4 oacc[8];
#pragma unroll
    for (int ni = 0; ni < 8; ni++)
      for (int r = 0; r < 4; r++) oacc[ni][r] = 0.f;
    float m_i = -1e30f, l_i = 0.f;

    for (int kb = 0; kb < nkb; kb++) {
      const int bb = kb & 1;
      __syncthreads();  // drains prefetch(kb) [compiler vmcnt], syncs buffers
      if (kb + 1 < nkb) {
        const int k0n = (kb + 1) * 64;
        const int nb = 1 - bb;
#pragma unroll
        for (int i = 0; i < 4; i++) {
          const int idx = tid + i * 256;
          const int key = idx >> 4, cc = (idx & 15) ^ (key & 15);
          gl_lds16(Kg + (size_t)(b * kT + k0n + key) * kD + h * kHD + cc * 8,
                   &sK[nb][idx * 8]);
        }
#pragma unroll
        for (int i = 0; i < 4; i++) {
          const int idx = tid + i * 256;
          const int hd = idx >> 3, cc = (idx & 7) ^ (hd & 7);
          gl_lds16(Vt + ((size_t)((b * kH + h) * kHD + hd)) * kT + k0n + cc * 8,
                   &sV[nb][idx * 8]);
        }
      }

      // S^T = K Q^T : lane holds S^T[key = s*16 + g*4 + r][q]
      f32x4 st[4];
#pragma unroll
      for (int s = 0; s < 4; s++)
        for (int r = 0; r < 4; r++) st[s][r] = 0.f;
#pragma unroll
      for (int s = 0; s < 4; s++) {
        const int key = s * 16 + q15;  // A-frag row for this lane
#pragma unroll
        for (int kk = 0; kk < 4; kk++) {
          bf16x8 kf = *(const bf16x8*)(
              &sK[bb][(key * 16 + ((kk * 4 + g) ^ (key & 15))) * 8]);
          st[s] = MFMA(kf, qf[kk], st[s]);
        }
      }
      // causal mask (diagonal tile only)
      if (kb == nkb - 1) {
        const int k0 = kb * 64;
#pragma unroll
        for (int s = 0; s < 4; s++)
          for (int r = 0; r < 4; r++)
            if (k0 + s * 16 + g * 4 + r > q) st[s][r] = -1e30f;
      }
      // online softmax (exp2 domain; Q pre-scaled). Per-lane row stats.
      float mx = -1e30f;
#pragma unroll
      for (int s = 0; s < 4; s++)
        for (int r = 0; r < 4; r++) mx = fmaxf(mx, st[s][r]);
      mx = fmaxf(mx, __shfl_xor(mx, 16, 64));
      mx = fmaxf(mx, __shfl_xor(mx, 32, 64));
      const float mn = fmaxf(m_i, mx);
      const float alpha = fast_exp2(m_i - mn);
      float rs = 0.f;
      union { bf16x8 v; unsigned short u[8]; } pkv[2];
#pragma unroll
      for (int s = 0; s < 4; s++)
        for (int r = 0; r < 4; r++) {
          const float p = fast_exp2(st[s][r] - mn);
          rs += p;
          pkv[s >> 1].u[(s & 1) * 4 + r] = f2bf(p);  // slot j=(s&1)*4+r
        }
      rs += __shfl_xor(rs, 16, 64);
      rs += __shfl_xor(rs, 32, 64);
      m_i = mn;
      l_i = l_i * alpha + rs;
#pragma unroll
      for (int ni = 0; ni < 8; ni++)
        for (int r = 0; r < 4; r++) oacc[ni][r] *= alpha;
      // O^T += V^T P^T with K=32 MFMA; A-frag slot (g,j) = key 32c+(j>>2)*16+4g+(j&3)
#pragma unroll
      for (int ni = 0; ni < 8; ni++) {
        const int hd = ni * 16 + q15;
        const int hx = hd & 7, base = hd * 8;
#pragma unroll
        for (int c = 0; c < 2; c++) {
          const int c4l = 8 * c + g;       // keys 32c+4g+0..3   (j=0..3)
          const int c4h = 8 * c + 4 + g;   // keys 32c+16+4g+0..3 (j=4..7)
          bf16x4 lo = *(const bf16x4*)(
              &sV[bb][(base + ((c4l >> 1) ^ hx)) * 8 + (c4l & 1) * 4]);
          bf16x4 hi = *(const bf16x4*)(
              &sV[bb][(base + ((c4h >> 1) ^ hx)) * 8 + (c4h & 1) * 4]);
          bf16x8 vf = __builtin_shufflevector(lo, hi, 0, 1, 2, 3, 4, 5, 6, 7);
          oacc[ni] = MFMA(vf, pkv[c].v, oacc[ni]);
        }
      }
    }
    // epilogue: O^T C-layout -> O[b][t=q][h*128 + hd], 4 contiguous d per lane
    const float inv = 1.f / l_i;
    unsigned short* Orow = O + (size_t)(b * kT + q) * kD + h * kHD;
#pragma unroll
    for (int ni = 0; ni < 8; ni++) {
      ushort4 o4;
      o4.x = f2bf(oacc[ni][0] * inv);
      o4.y = f2bf(oacc[ni][1] * inv);
      o4.z = f2bf(oacc[ni][2] * inv);
      o4.w = f2bf(oacc[ni][3] * inv);
      *(ushort4*)(Orow + ni * 16 + g * 4) = o4;
    }
  }
}

extern "C" void kernel_launch(void* const* d_in, const int* in_sizes, int n_in,
                              void* d_out, int out_size, void* d_ws, size_t ws_size,
                              hipStream_t stream) {
  const float* x       = (const float*)d_in[0];
  const float* Wq      = (const float*)d_in[1];
  const float* bq      = (const float*)d_in[2];
  const float* Wk      = (const float*)d_in[3];
  const float* bk      = (const float*)d_in[4];
  // d_in[5] Wvq, d_in[6] bvq, d_in[7] v_keys: dead (top_k selects all NVK)
  const float* v_embed = (const float*)d_in[8];
  const float* Wo      = (const float*)d_in[9];
  const float* bo      = (const float*)d_in[10];
  float* out = (float*)d_out;

  char* w = (char*)d_ws;
  unsigned short* xb  = (unsigned short*)w; w += (size_t)kBT * kD * 2;  // 16MB
  unsigned short* qb  = (unsigned short*)w; w += (size_t)kBT * kD * 2;
  unsigned short* kb  = (unsigned short*)w; w += (size_t)kBT * kD * 2;
  unsigned short* ob  = (unsigned short*)w; w += (size_t)kBT * kD * 2;
  unsigned short* vtb = (unsigned short*)w; w += (size_t)kBT * kD * 2;
  unsigned short* wqb = (unsigned short*)w; w += (size_t)kD * kD * 2;   // 8MB
  unsigned short* wkb = (unsigned short*)w; w += (size_t)kD * kD * 2;
  unsigned short* wob = (unsigned short*)w; w += (size_t)kD * kD * 2;

  cvt_kernel<<<kBT * kD / 1024, 256, 0, stream>>>(x, xb, kBT * kD / 4);
  cvt3_kernel<<<dim3(kD * kD / 1024, 3), 256, 0, stream>>>(
      Wq, Wk, Wo, wqb, wkb, wob, kD * kD / 4);
  make_vt_kernel<<<dim3(kT / 64, kH, kB), 256, 0, stream>>>(x, v_embed, vtb);

  // fold softmax scale (1/sqrt(HD) * log2(e), exp2 domain) into Q projection
  const float scaleQ = 0.08838834764831845f * 1.4426950408889634f;
  // fused Q+K projections: grid.z picks weights/bias/output
  gemm_bt<true, true><<<dim3(kD / 128, kBT / 128, 2), 256, 0, stream>>>(
      xb, wqb, wkb, bq, bk, qb, kb, scaleQ, 1.0f);

  attn2_kernel<<<dim3(16, kH, kB), 256, 0, stream>>>(qb, kb, vtb, ob);

  gemm_bt<false, false><<<dim3(kD / 128, kBT / 128, 1), 256, 0, stream>>>(
      ob, wob, nullptr, bo, nullptr, out, nullptr, 1.0f, 1.0f);
}

// Round 5
// 337.615 us; speedup vs baseline: 1.4003x; 1.0914x over previous
//
#include <hip/hip_runtime.h>
#include <hip/hip_bf16.h>

#define DEV __device__ __forceinline__

typedef __bf16 bf16x8 __attribute__((ext_vector_type(8)));
typedef __bf16 bf16x4 __attribute__((ext_vector_type(4)));
typedef float f32x4 __attribute__((ext_vector_type(4)));

static constexpr int kB = 2, kT = 2048, kD = 2048, kH = 16, kHD = 128;
static constexpr int kBT = kB * kT;  // 4096

// fast 2^x: v_exp_f32 computes exp2 natively on gfx950
#if __has_builtin(__builtin_amdgcn_exp2f)
DEV float fast_exp2(float x) { return __builtin_amdgcn_exp2f(x); }
#else
DEV float fast_exp2(float x) { return exp2f(x); }
#endif

DEV unsigned short f2bf(float f) {
  union { __hip_bfloat16 h; unsigned short u; } cv;
  cv.h = __float2bfloat16(f);
  return cv.u;
}

// async global->LDS, 16B per lane. LDS dest must be wave-uniform base + lane*16.
DEV void gl_lds16(const void* g, void* l) {
  __builtin_amdgcn_global_load_lds(
      (const __attribute__((address_space(1))) unsigned int*)g,
      (__attribute__((address_space(3))) unsigned int*)l, 16, 0, 0);
}

#define MFMA(a, b, c) __builtin_amdgcn_mfma_f32_16x16x32_bf16(a, b, c, 0, 0, 0)

// bank swizzle for 128x32 bf16 tiles staged via global_load_lds:
// slot = row*4 + (chunk ^ swz(row)); swz covers row bits 0..3 so frag-read
// lanes {i,i+4,i+8,i+12} land in distinct 16B chunks -> 2-way max (free).
DEV int swz4(int row) { return (row ^ (row >> 2)) & 3; }

// ---------------- fp32 -> bf16 conversion, 4 buffers in one dispatch --------
__global__ __launch_bounds__(256) void cvt4_kernel(
    const float* __restrict__ s0, const float* __restrict__ s1,
    const float* __restrict__ s2, const float* __restrict__ s3,
    unsigned short* __restrict__ d0, unsigned short* __restrict__ d1,
    unsigned short* __restrict__ d2, unsigned short* __restrict__ d3,
    int n0, int n1) {
  const int y = blockIdx.y;
  const float* s = y == 0 ? s0 : y == 1 ? s1 : y == 2 ? s2 : s3;
  unsigned short* d = y == 0 ? d0 : y == 1 ? d1 : y == 2 ? d2 : d3;
  const int n4 = y == 0 ? n0 : n1;
  int i = blockIdx.x * 256 + threadIdx.x;
  if (i >= n4) return;
  float4 v = ((const float4*)s)[i];
  ushort4 o;
  o.x = f2bf(v.x); o.y = f2bf(v.y); o.z = f2bf(v.z); o.w = f2bf(v.w);
  ((ushort4*)d)[i] = o;
}

// ------------- V^T = (x * c) transposed to [b][h][hd][T], bf16 -------------
// top_k with TOPK==NVK==4 selects ALL rows -> c[d] = 2*sum_{k<4} v_embed[k][d].
// Tiled transpose through LDS: coalesced float4 reads of x (lane=d), scatter
// into [hd][t] LDS, coalesced 16B writes of vt (lane=t).
__global__ __launch_bounds__(256) void make_vt_kernel(
    const float* __restrict__ x, const float* __restrict__ v_embed,
    unsigned short* __restrict__ vt) {
  __shared__ __align__(16) unsigned short sT[128 * 72];  // [hd][t], stride 72
  const int t0 = blockIdx.x * 64, h = blockIdx.y, b = blockIdx.z;
  const int tid = threadIdx.x;
  const int d4 = tid & 31, r8 = tid >> 5;
  const int dg = h * kHD + d4 * 4;
  float4 e0 = *(const float4*)(v_embed + dg);
  float4 e1 = *(const float4*)(v_embed + kD + dg);
  float4 e2 = *(const float4*)(v_embed + 2 * kD + dg);
  float4 e3 = *(const float4*)(v_embed + 3 * kD + dg);
  float4 c4;
  c4.x = 2.f * (e0.x + e1.x + e2.x + e3.x);
  c4.y = 2.f * (e0.y + e1.y + e2.y + e3.y);
  c4.z = 2.f * (e0.z + e1.z + e2.z + e3.z);
  c4.w = 2.f * (e0.w + e1.w + e2.w + e3.w);
#pragma unroll
  for (int it = 0; it < 8; it++) {
    const int t = r8 + it * 8;  // 0..63
    float4 v = *(const float4*)(x + (size_t)(b * kT + t0 + t) * kD + dg);
    sT[(d4 * 4 + 0) * 72 + t] = f2bf(v.x * c4.x);
    sT[(d4 * 4 + 1) * 72 + t] = f2bf(v.y * c4.y);
    sT[(d4 * 4 + 2) * 72 + t] = f2bf(v.z * c4.z);
    sT[(d4 * 4 + 3) * 72 + t] = f2bf(v.w * c4.w);
  }
  __syncthreads();
#pragma unroll
  for (int it = 0; it < 4; it++) {
    const int hd = (tid >> 3) + it * 32;
    const int tt = (tid & 7) * 8;
    bf16x8 vv = *(const bf16x8*)(sT + hd * 72 + tt);
    *(bf16x8*)(vt + ((size_t)((b * kH + h) * kHD + hd)) * kT + t0 + tt) = vv;
  }
}

// ---------------- C[m,n] = (sum_k A[m,k]*B[n,k] + bias[n]) * scale ----------
// 128x128 tile, BK=32, 4 waves (2x2), 16x16x32 bf16 MFMA, global_load_lds w=16,
// swz4 chunk swizzle (2-way max bank aliasing on frag reads).
template <bool BF16OUT, bool FUSED2>
__global__ __launch_bounds__(256, 4) void gemm_bt(
    const unsigned short* __restrict__ A, const unsigned short* __restrict__ B1,
    const unsigned short* __restrict__ B2, const float* __restrict__ bias1,
    const float* __restrict__ bias2, void* __restrict__ C1, void* __restrict__ C2,
    float scale1, float scale2) {
  constexpr int N = kD, K = kD;
  __shared__ __align__(16) unsigned short As[128 * 32], Bs[128 * 32];
  const unsigned short* Bm = (FUSED2 && blockIdx.z) ? B2 : B1;
  const float* bias = (FUSED2 && blockIdx.z) ? bias2 : bias1;
  void* Cout = (FUSED2 && blockIdx.z) ? C2 : C1;
  const float scale = (FUSED2 && blockIdx.z) ? scale2 : scale1;
  const int tid = threadIdx.x;
  const int lane = tid & 63, wave = tid >> 6;
  const int wr = wave >> 1, wc = wave & 1;
  const int m0 = blockIdx.y * 128, n0 = blockIdx.x * 128;
  const int frow = lane & 15, fc = lane >> 4;

  f32x4 acc[4][4];
  for (int i = 0; i < 4; i++)
    for (int j = 0; j < 4; j++)
      for (int r = 0; r < 4; r++) acc[i][j][r] = 0.f;

  const int r0 = tid >> 2, c0 = (tid & 3) ^ swz4(r0);
  const int p1 = tid + 256;
  const int r1 = p1 >> 2, c1 = (p1 & 3) ^ swz4(r1);

  const unsigned short* Ab = A + (size_t)m0 * K;
  const unsigned short* Bb = Bm + (size_t)n0 * K;

  for (int k0 = 0; k0 < K; k0 += 32) {
    __syncthreads();
    gl_lds16(Ab + (size_t)r0 * K + k0 + c0 * 8, As + tid * 8);
    gl_lds16(Ab + (size_t)r1 * K + k0 + c1 * 8, As + p1 * 8);
    gl_lds16(Bb + (size_t)r0 * K + k0 + c0 * 8, Bs + tid * 8);
    gl_lds16(Bb + (size_t)r1 * K + k0 + c1 * 8, Bs + p1 * 8);
    __syncthreads();
    bf16x8 af[4], bfr[4];
    for (int mi = 0; mi < 4; mi++) {
      int row = wr * 64 + mi * 16 + frow;
      af[mi] = *(const bf16x8*)(As + (row * 4 + (fc ^ swz4(row))) * 8);
    }
    for (int ni = 0; ni < 4; ni++) {
      int row = wc * 64 + ni * 16 + frow;
      bfr[ni] = *(const bf16x8*)(Bs + (row * 4 + (fc ^ swz4(row))) * 8);
    }
    for (int mi = 0; mi < 4; mi++)
      for (int ni = 0; ni < 4; ni++)
        acc[mi][ni] = MFMA(af[mi], bfr[ni], acc[mi][ni]);
  }
  // epilogue: C/D layout col=lane&15, row=(lane>>4)*4+reg
  for (int ni = 0; ni < 4; ni++) {
    const int n = n0 + wc * 64 + ni * 16 + frow;
    const float bs = bias[n];
    for (int mi = 0; mi < 4; mi++) {
      const int mb = m0 + wr * 64 + mi * 16 + fc * 4;
      for (int r = 0; r < 4; r++) {
        const float v = (acc[mi][ni][r] + bs) * scale;
        if (BF16OUT)
          ((unsigned short*)Cout)[(size_t)(mb + r) * N + n] = f2bf(v);
        else
          ((float*)Cout)[(size_t)(mb + r) * N + n] = v;
      }
    }
  }
}

// ---------------- flash attention v2, causal, S^T formulation ----------------
// Q is PRE-SCALED by (1/sqrt(HD))*log2(e); softmax in exp2 domain.
// 1-D grid 512, XCD-swizzled: all 16 pi-blocks of one (b,h) land on one XCD
// (bid&7 = XCD round-robin) so K/V (1MB) is fetched into that L2 once.
// Each block: paired q-tiles (31-pi, pi) -> uniform 33 k-tile units.
// PV via slot remap onto the K=32 MFMA (see R4 notes).
__global__ __launch_bounds__(256, 2) void attn2_kernel(
    const unsigned short* __restrict__ Q, const unsigned short* __restrict__ Kg,
    const unsigned short* __restrict__ Vt, unsigned short* __restrict__ O) {
  __shared__ __align__(16) unsigned short sK[2][64 * 128];  // [key][hd], swizzled
  __shared__ __align__(16) unsigned short sV[2][64 * 128];  // [hd][key], swizzled
  const int tid = threadIdx.x, l = tid & 63, w = tid >> 6;
  const int g = l >> 4, q15 = l & 15;
  const int bid = blockIdx.x;
  const int xcd = bid & 7, rest = bid >> 3;
  const int gidx = xcd + 8 * (rest & 3);  // (b,h) group 0..31
  const int pi = rest >> 2;               // 0..15
  const int h = gidx & 15, b = gidx >> 4;

  for (int half = 0; half < 2; half++) {
    const int qt = half == 0 ? (31 - pi) : pi;
    const int q0 = qt * 64;
    const int nkb = qt + 1;
    const int q = q0 + w * 16 + q15;  // this lane's q column

    __syncthreads();  // buffer reuse safety across halves
    // stage tile 0 -> buf 0
    for (int i = 0; i < 4; i++) {
      const int idx = tid + i * 256;
      const int key = idx >> 4, cc = (idx & 15) ^ (key & 15);
      gl_lds16(Kg + (size_t)(b * kT + key) * kD + h * kHD + cc * 8,
               &sK[0][idx * 8]);
    }
    for (int i = 0; i < 4; i++) {
      const int idx = tid + i * 256;
      const int hd = idx >> 3;
      const int cc = (idx & 7) ^ (hd & 7) ^ (((hd >> 3) & 1) << 2);
      gl_lds16(Vt + ((size_t)((b * kH + h) * kHD + hd)) * kT + cc * 8,
               &sV[0][idx * 8]);
    }

    // Q B-frags (lane holds Q[q][hd = kk*32 + g*8 .. +7])
    bf16x8 qf[4];
    const unsigned short* Qrow = Q + (size_t)(b * kT + q) * kD + h * kHD;
#pragma unroll
    for (int kk = 0; kk < 4; kk++)
      qf[kk] = *(const bf16x8*)(Qrow + kk * 32 + g * 8);

    f32x4 oacc[8];
#pragma unroll
    for (int ni = 0; ni < 8; ni++)
      for (int r = 0; r < 4; r++) oacc[ni][r] = 0.f;
    float m_i = -1e30f, l_i = 0.f;

    for (int kb = 0; kb < nkb; kb++) {
      const int bb = kb & 1;
      __syncthreads();  // drains prefetch(kb) [compiler vmcnt], syncs buffers
      if (kb + 1 < nkb) {
        const int k0n = (kb + 1) * 64;
        const int nb = 1 - bb;
#pragma unroll
        for (int i = 0; i < 4; i++) {
          const int idx = tid + i * 256;
          const int key = idx >> 4, cc = (idx & 15) ^ (key & 15);
          gl_lds16(Kg + (size_t)(b * kT + k0n + key) * kD + h * kHD + cc * 8,
                   &sK[nb][idx * 8]);
        }
#pragma unroll
        for (int i = 0; i < 4; i++) {
          const int idx = tid + i * 256;
          const int hd = idx >> 3;
          const int cc = (idx & 7) ^ (hd & 7) ^ (((hd >> 3) & 1) << 2);
          gl_lds16(Vt + ((size_t)((b * kH + h) * kHD + hd)) * kT + k0n + cc * 8,
                   &sV[nb][idx * 8]);
        }
      }

      // S^T = K Q^T : lane holds S^T[key = s*16 + g*4 + r][q]
      f32x4 st[4];
#pragma unroll
      for (int s = 0; s < 4; s++)
        for (int r = 0; r < 4; r++) st[s][r] = 0.f;
#pragma unroll
      for (int s = 0; s < 4; s++) {
        const int key = s * 16 + q15;  // A-frag row for this lane
#pragma unroll
        for (int kk = 0; kk < 4; kk++) {
          bf16x8 kf = *(const bf16x8*)(
              &sK[bb][(key * 16 + ((kk * 4 + g) ^ (key & 15))) * 8]);
          st[s] = MFMA(kf, qf[kk], st[s]);
        }
      }
      // causal mask (diagonal tile only)
      if (kb == nkb - 1) {
        const int k0 = kb * 64;
#pragma unroll
        for (int s = 0; s < 4; s++)
          for (int r = 0; r < 4; r++)
            if (k0 + s * 16 + g * 4 + r > q) st[s][r] = -1e30f;
      }
      // online softmax (exp2 domain; Q pre-scaled). Per-lane row stats.
      float mx = -1e30f;
#pragma unroll
      for (int s = 0; s < 4; s++)
        for (int r = 0; r < 4; r++) mx = fmaxf(mx, st[s][r]);
      mx = fmaxf(mx, __shfl_xor(mx, 16, 64));
      mx = fmaxf(mx, __shfl_xor(mx, 32, 64));
      const float mn = fmaxf(m_i, mx);
      const float alpha = fast_exp2(m_i - mn);
      float rs = 0.f;
      union { bf16x8 v; unsigned short u[8]; } pkv[2];
#pragma unroll
      for (int s = 0; s < 4; s++)
        for (int r = 0; r < 4; r++) {
          const float p = fast_exp2(st[s][r] - mn);
          rs += p;
          pkv[s >> 1].u[(s & 1) * 4 + r] = f2bf(p);  // slot j=(s&1)*4+r
        }
      rs += __shfl_xor(rs, 16, 64);
      rs += __shfl_xor(rs, 32, 64);
      m_i = mn;
      l_i = l_i * alpha + rs;
#pragma unroll
      for (int ni = 0; ni < 8; ni++)
        for (int r = 0; r < 4; r++) oacc[ni][r] *= alpha;
      // O^T += V^T P^T with K=32 MFMA; A-frag slot (g,j) = key 32c+(j>>2)*16+4g+(j&3)
#pragma unroll
      for (int ni = 0; ni < 8; ni++) {
        const int hd = ni * 16 + q15;
        const int hx = (hd & 7) ^ (((hd >> 3) & 1) << 2), base = hd * 8;
#pragma unroll
        for (int c = 0; c < 2; c++) {
          const int c4l = 8 * c + g;       // keys 32c+4g+0..3   (j=0..3)
          const int c4h = 8 * c + 4 + g;   // keys 32c+16+4g+0..3 (j=4..7)
          bf16x4 lo = *(const bf16x4*)(
              &sV[bb][(base + ((c4l >> 1) ^ hx)) * 8 + (c4l & 1) * 4]);
          bf16x4 hi = *(const bf16x4*)(
              &sV[bb][(base + ((c4h >> 1) ^ hx)) * 8 + (c4h & 1) * 4]);
          bf16x8 vf = __builtin_shufflevector(lo, hi, 0, 1, 2, 3, 4, 5, 6, 7);
          oacc[ni] = MFMA(vf, pkv[c].v, oacc[ni]);
        }
      }
    }
    // epilogue: O^T C-layout -> O[b][t=q][h*128 + hd], 4 contiguous d per lane
    const float inv = 1.f / l_i;
    unsigned short* Orow = O + (size_t)(b * kT + q) * kD + h * kHD;
#pragma unroll
    for (int ni = 0; ni < 8; ni++) {
      ushort4 o4;
      o4.x = f2bf(oacc[ni][0] * inv);
      o4.y = f2bf(oacc[ni][1] * inv);
      o4.z = f2bf(oacc[ni][2] * inv);
      o4.w = f2bf(oacc[ni][3] * inv);
      *(ushort4*)(Orow + ni * 16 + g * 4) = o4;
    }
  }
}

extern "C" void kernel_launch(void* const* d_in, const int* in_sizes, int n_in,
                              void* d_out, int out_size, void* d_ws, size_t ws_size,
                              hipStream_t stream) {
  const float* x       = (const float*)d_in[0];
  const float* Wq      = (const float*)d_in[1];
  const float* bq      = (const float*)d_in[2];
  const float* Wk      = (const float*)d_in[3];
  const float* bk      = (const float*)d_in[4];
  // d_in[5] Wvq, d_in[6] bvq, d_in[7] v_keys: dead (top_k selects all NVK)
  const float* v_embed = (const float*)d_in[8];
  const float* Wo      = (const float*)d_in[9];
  const float* bo      = (const float*)d_in[10];
  float* out = (float*)d_out;

  char* w = (char*)d_ws;
  unsigned short* xb  = (unsigned short*)w; w += (size_t)kBT * kD * 2;  // 16MB
  unsigned short* qb  = (unsigned short*)w; w += (size_t)kBT * kD * 2;
  unsigned short* kb  = (unsigned short*)w; w += (size_t)kBT * kD * 2;
  unsigned short* ob  = (unsigned short*)w; w += (size_t)kBT * kD * 2;
  unsigned short* vtb = (unsigned short*)w; w += (size_t)kBT * kD * 2;
  unsigned short* wqb = (unsigned short*)w; w += (size_t)kD * kD * 2;   // 8MB
  unsigned short* wkb = (unsigned short*)w; w += (size_t)kD * kD * 2;
  unsigned short* wob = (unsigned short*)w; w += (size_t)kD * kD * 2;

  // all fp32->bf16 conversions in one dispatch (x + 3 weight matrices)
  cvt4_kernel<<<dim3(kBT * kD / 1024, 4), 256, 0, stream>>>(
      x, Wq, Wk, Wo, xb, wqb, wkb, wob, kBT * kD / 4, kD * kD / 4);
  make_vt_kernel<<<dim3(kT / 64, kH, kB), 256, 0, stream>>>(x, v_embed, vtb);

  // fold softmax scale (1/sqrt(HD) * log2(e), exp2 domain) into Q projection
  const float scaleQ = 0.08838834764831845f * 1.4426950408889634f;
  // fused Q+K projections: grid.z picks weights/bias/output
  gemm_bt<true, true><<<dim3(kD / 128, kBT / 128, 2), 256, 0, stream>>>(
      xb, wqb, wkb, bq, bk, qb, kb, scaleQ, 1.0f);

  attn2_kernel<<<dim3(512), 256, 0, stream>>>(qb, kb, vtb, ob);

  gemm_bt<false, false><<<dim3(kD / 128, kBT / 128, 1), 256, 0, stream>>>(
      ob, wob, nullptr, bo, nullptr, out, nullptr, 1.0f, 1.0f);
}